// Round 1
// baseline (925.577 us; speedup 1.0000x reference)
//
#include <hip/hip_runtime.h>
#include <hip/hip_bf16.h>

#define N_NODES   10000
#define N_EDGES   320000
#define DIM       256
#define EDGE_DIM  64
#define FF_HIDDEN 512
#define GAMMA     0.5f

// ---------------------------------------------------------------------------
// Edge-index dtype probe: int64 little-endian with values <2^31 has zero high
// words; int32 random values in [0,10000) make P(1024 zeros) ~ 0.
__global__ __launch_bounds__(256) void detect_kernel(const unsigned* __restrict__ ei,
                                                     int* __restrict__ flag)
{
    __shared__ int bad;
    if (threadIdx.x == 0) bad = 0;
    __syncthreads();
    int b = 0;
    for (int i = threadIdx.x; i < 1024; i += 256)
        if (ei[2 * i + 1] != 0u) b = 1;
    if (b) atomicAdd(&bad, 1);
    __syncthreads();
    if (threadIdx.x == 0) *flag = (bad == 0) ? 1 : 0;
}

// Convert edge_index to int32 src/dst and count in-degrees.
__global__ __launch_bounds__(256) void convert_kernel(const unsigned* __restrict__ ei,
                                                      const int* __restrict__ flag,
                                                      int* __restrict__ src, int* __restrict__ dst,
                                                      int* __restrict__ counts)
{
    const int i = blockIdx.x * 256 + threadIdx.x;
    if (i >= N_EDGES) return;
    const int f = *flag;
    int s, d;
    if (f) { s = (int)ei[2 * i]; d = (int)ei[2 * (N_EDGES + i)]; }
    else   { s = (int)ei[i];     d = (int)ei[N_EDGES + i]; }
    src[i] = s;
    dst[i] = d;
    atomicAdd(&counts[d], 1);
}

// Exclusive scan of 10000 counts -> row_start[0..N], single block.
__global__ __launch_bounds__(256) void scan_kernel(const int* __restrict__ counts,
                                                   int* __restrict__ row_start)
{
    __shared__ int lds[256];
    const int t = threadIdx.x;
    int vals[40];
    int tot = 0;
    const int base = t * 40;
#pragma unroll
    for (int j = 0; j < 40; ++j) {
        const int idx = base + j;
        const int c = (idx < N_NODES) ? counts[idx] : 0;
        vals[j] = tot;   // exclusive within-thread prefix
        tot += c;
    }
    lds[t] = tot;
    __syncthreads();
    for (int off = 1; off < 256; off <<= 1) {
        const int tmp = (t >= off) ? lds[t - off] : 0;
        __syncthreads();
        lds[t] += tmp;
        __syncthreads();
    }
    const int ebase = lds[t] - tot;
#pragma unroll
    for (int j = 0; j < 40; ++j) {
        const int idx = base + j;
        if (idx < N_NODES) row_start[idx] = ebase + vals[j];
    }
    if (t == 0) row_start[N_NODES] = N_EDGES;
}

__global__ __launch_bounds__(256) void fill_kernel(const int* __restrict__ src,
                                                   const int* __restrict__ dst,
                                                   const int* __restrict__ row_start,
                                                   int* __restrict__ fillc,
                                                   int* __restrict__ csr_eid,
                                                   int* __restrict__ csr_src)
{
    const int i = blockIdx.x * 256 + threadIdx.x;
    if (i >= N_EDGES) return;
    const int d = dst[i];
    const int pos = atomicAdd(&fillc[d], 1);
    const int slot = row_start[d] + pos;
    csr_eid[slot] = i;
    csr_src[slot] = src[i];
}

// ---------------------------------------------------------------------------
// Broadcast GEMM: out[m][n] = sum_k A[m][k] * W[k][n].
// Thread owns n = c*256 + tid; 64-deep W column chunk lives in VGPRs (fully
// unrolled -> register-resident). A-row loads are block-uniform -> s_load.
// K = NCHUNKS*64, chunk-outer with single-writer RMW partials in out.
// MODE 0: f32 out.  MODE 1: bf16 out (NCHUNKS==1).  MODE 2: f32 out + ff2
// epilogue on last chunk: out = epi_x + relu(epi_a + total).
template <int COLS, int NCHUNKS, bool RELU_A, int MODE>
__global__ __launch_bounds__(256) void gemm_bcast(const float* __restrict__ A,
                                                  const float* __restrict__ W,
                                                  void* __restrict__ outv,
                                                  int M, int K, int N,
                                                  const float* __restrict__ epi_a,
                                                  const float* __restrict__ epi_x)
{
    const int t = threadIdx.x;
    float w[COLS][64];
    for (int ch = 0; ch < NCHUNKS; ++ch) {
        const int k0 = ch * 64;
#pragma unroll
        for (int c = 0; c < COLS; ++c)
#pragma unroll
            for (int j = 0; j < 64; ++j)
                w[c][j] = W[(size_t)(k0 + j) * N + c * 256 + t];
        for (int m = blockIdx.x; m < M; m += gridDim.x) {
            const float* __restrict__ a = A + (size_t)m * K + k0;
            float acc[COLS];
#pragma unroll
            for (int c = 0; c < COLS; ++c) acc[c] = 0.f;
#pragma unroll
            for (int j = 0; j < 64; ++j) {
                float av = a[j];
                if (RELU_A) av = fmaxf(av, 0.f);
#pragma unroll
                for (int c = 0; c < COLS; ++c) acc[c] = fmaf(av, w[c][j], acc[c]);
            }
#pragma unroll
            for (int c = 0; c < COLS; ++c) {
                const size_t oi = (size_t)m * N + c * 256 + t;
                if (MODE == 1) {
                    ((__hip_bfloat16*)outv)[oi] = __float2bfloat16(acc[c]);
                } else {
                    float* __restrict__ out = (float*)outv;
                    if (NCHUNKS > 1 && ch == 0) {
                        out[oi] = acc[c];
                    } else {
                        float v = (NCHUNKS == 1) ? acc[c] : out[oi] + acc[c];
                        if (MODE == 2 && ch == NCHUNKS - 1) {
                            v += epi_a[oi];
                            v = fmaxf(v, 0.f) + epi_x[oi];
                        }
                        out[oi] = v;
                    }
                }
            }
        }
    }
}

// ---------------------------------------------------------------------------
// One propagation hop: h_out[n][d] = sum_{e->n} relu(h_prev1[src][d] + e[d])
//                                    - GAMMA * deg[n] * h_prev2[n][d]
__global__ __launch_bounds__(256) void hop_kernel(const float* __restrict__ h_prev1,
                                                  const float* __restrict__ h_prev2,
                                                  const __hip_bfloat16* __restrict__ e,
                                                  const int* __restrict__ row_start,
                                                  const int* __restrict__ csr_eid,
                                                  const int* __restrict__ csr_src,
                                                  float* __restrict__ h_out)
{
    const int n = blockIdx.x;
    const int t = threadIdx.x;
    const int rb = row_start[n];
    const int re = row_start[n + 1];
    float acc = 0.f;
    for (int s = rb; s < re; ++s) {
        const int eid = csr_eid[s];
        const int sr  = csr_src[s];
        const float v = h_prev1[(size_t)sr * DIM + t] +
                        __bfloat162float(e[(size_t)eid * DIM + t]);
        acc += fmaxf(v, 0.f);
    }
    float r = acc;
    if (h_prev2) {
        const float deg = (float)(re - rb);
        r -= GAMMA * deg * h_prev2[(size_t)n * DIM + t];
    }
    h_out[(size_t)n * DIM + t] = r;
}

// ---------------------------------------------------------------------------
// Hop attention: wave w == head w (64 lanes == 64 head dims).
__global__ __launch_bounds__(256) void attn_kernel(const float* __restrict__ h0,
                                                   const float* __restrict__ h1,
                                                   const float* __restrict__ h2,
                                                   const float* __restrict__ h3,
                                                   const float* __restrict__ att_a,
                                                   float* __restrict__ out)
{
    const int n = blockIdx.x;
    const int t = threadIdx.x;
    const size_t i = (size_t)n * DIM + t;
    const float q = h0[i];
    float hk[4];
    hk[0] = q; hk[1] = h1[i]; hk[2] = h2[i]; hk[3] = h3[i];
    const float a = att_a[t];   // att_a flat (4,64) row-major == head*64+d
    float sc[4];
#pragma unroll
    for (int k = 0; k < 4; ++k) {
        float v = tanhf(hk[k] + q) * a;
#pragma unroll
        for (int off = 32; off > 0; off >>= 1)
            v += __shfl_xor(v, off, 64);
        sc[k] = v;
    }
    const float mx = fmaxf(fmaxf(sc[0], sc[1]), fmaxf(sc[2], sc[3]));
    float ex[4], se = 0.f;
#pragma unroll
    for (int k = 0; k < 4; ++k) { ex[k] = __expf(sc[k] - mx); se += ex[k]; }
    const float inv = 1.f / se;
    float o = 0.f;
#pragma unroll
    for (int k = 0; k < 4; ++k) o += ex[k] * inv * hk[k];
    out[i] = o;
}

// ---------------------------------------------------------------------------
extern "C" void kernel_launch(void* const* d_in, const int* in_sizes, int n_in,
                              void* d_out, int out_size, void* d_ws, size_t ws_size,
                              hipStream_t stream)
{
    const float*    x         = (const float*)d_in[0];
    const unsigned* ei        = (const unsigned*)d_in[1];
    const float*    edge_attr = (const float*)d_in[2];
    const float*    W_x       = (const float*)d_in[3];
    const float*    W_e       = (const float*)d_in[4];
    const float*    att_a     = (const float*)d_in[5];
    const float*    W_ff1     = (const float*)d_in[6];
    const float*    W_ff2     = (const float*)d_in[7];

    char* ws = (char*)d_ws;
    size_t off = 0;
    auto alloc = [&](size_t bytes) -> void* {
        void* p = ws + off;
        off = (off + bytes + 255) & ~(size_t)255;
        return p;
    };
    int*   flag      = (int*)alloc(4);
    int*   src32     = (int*)alloc((size_t)N_EDGES * 4);
    int*   dst32     = (int*)alloc((size_t)N_EDGES * 4);
    int*   counts    = (int*)alloc((size_t)2 * N_NODES * 4);  // counts + fill, contiguous
    int*   fillc     = counts + N_NODES;
    int*   row_start = (int*)alloc((size_t)(N_NODES + 1) * 4);
    int*   csr_eid   = (int*)alloc((size_t)N_EDGES * 4);
    int*   csr_src   = (int*)alloc((size_t)N_EDGES * 4);
    float* h0        = (float*)alloc((size_t)N_NODES * DIM * 4);
    float* h1        = (float*)alloc((size_t)N_NODES * DIM * 4);
    float* h2        = (float*)alloc((size_t)N_NODES * DIM * 4);
    float* h3        = (float*)alloc((size_t)N_NODES * DIM * 4);
    __hip_bfloat16* e_bf = (__hip_bfloat16*)alloc((size_t)N_EDGES * DIM * 2);
    float* attn_out  = (float*)alloc((size_t)N_NODES * DIM * 4);
    float* hidden    = (float*)alloc((size_t)N_NODES * FF_HIDDEN * 4);
    if (off > ws_size) return;  // workspace too small: bail cleanly

    const int egrid = (N_EDGES + 255) / 256;

    hipMemsetAsync(counts, 0, (size_t)2 * N_NODES * 4, stream);
    detect_kernel<<<1, 256, 0, stream>>>(ei, flag);
    convert_kernel<<<egrid, 256, 0, stream>>>(ei, flag, src32, dst32, counts);
    scan_kernel<<<1, 256, 0, stream>>>(counts, row_start);
    fill_kernel<<<egrid, 256, 0, stream>>>(src32, dst32, row_start, fillc, csr_eid, csr_src);

    // h0 = x @ W_x   (M=10000, K=256, N=256)
    gemm_bcast<1, 4, false, 0><<<640, 256, 0, stream>>>(x, W_x, h0,
        N_NODES, DIM, DIM, nullptr, nullptr);
    // e = edge_attr @ W_e -> bf16   (M=320000, K=64, N=256)
    gemm_bcast<1, 1, false, 1><<<2048, 256, 0, stream>>>(edge_attr, W_e, e_bf,
        N_EDGES, EDGE_DIM, DIM, nullptr, nullptr);

    hop_kernel<<<N_NODES, 256, 0, stream>>>(h0, nullptr, e_bf, row_start, csr_eid, csr_src, h1);
    hop_kernel<<<N_NODES, 256, 0, stream>>>(h1, h0,      e_bf, row_start, csr_eid, csr_src, h2);
    hop_kernel<<<N_NODES, 256, 0, stream>>>(h2, h1,      e_bf, row_start, csr_eid, csr_src, h3);

    attn_kernel<<<N_NODES, 256, 0, stream>>>(h0, h1, h2, h3, att_a, attn_out);

    // hidden = attn_out @ W_ff1   (M=10000, K=256, N=512)
    gemm_bcast<2, 4, false, 0><<<640, 256, 0, stream>>>(attn_out, W_ff1, hidden,
        N_NODES, DIM, FF_HIDDEN, nullptr, nullptr);
    // d_out = x + relu(attn_out + relu(hidden) @ W_ff2)   (M=10000, K=512, N=256)
    gemm_bcast<1, 8, true, 2><<<640, 256, 0, stream>>>(hidden, W_ff2, d_out,
        N_NODES, FF_HIDDEN, DIM, attn_out, x);
}

// Round 3
// 479.429 us; speedup vs baseline: 1.9306x; 1.9306x over previous
//
#include <hip/hip_runtime.h>
#include <hip/hip_bf16.h>

#define N_NODES   10000
#define N_EDGES   320000
#define DIM       256
#define EDGE_DIM  64
#define FF_HIDDEN 512
#define GAMMA     0.5f

typedef __attribute__((ext_vector_type(8))) short bf16x8;
typedef __attribute__((ext_vector_type(4))) float f32x4;

static __device__ __forceinline__ unsigned short f2b(float f)
{
    union { __hip_bfloat16 b; unsigned short u; } c;
    c.b = __float2bfloat16(f);
    return c.u;
}

// ---------------------------------------------------------------------------
// Edge-index dtype probe: int64 little-endian with values <2^31 has zero high
// words; int32 random values in [0,10000) make P(1024 zeros) ~ 0.
__global__ __launch_bounds__(256) void detect_kernel(const unsigned* __restrict__ ei,
                                                     int* __restrict__ flag)
{
    __shared__ int bad;
    if (threadIdx.x == 0) bad = 0;
    __syncthreads();
    int b = 0;
    for (int i = threadIdx.x; i < 1024; i += 256)
        if (ei[2 * i + 1] != 0u) b = 1;
    if (b) atomicAdd(&bad, 1);
    __syncthreads();
    if (threadIdx.x == 0) *flag = (bad == 0) ? 1 : 0;
}

__global__ __launch_bounds__(256) void convert_kernel(const unsigned* __restrict__ ei,
                                                      const int* __restrict__ flag,
                                                      int* __restrict__ src, int* __restrict__ dst,
                                                      int* __restrict__ counts)
{
    const int i = blockIdx.x * 256 + threadIdx.x;
    if (i >= N_EDGES) return;
    const int f = *flag;
    int s, d;
    if (f) { s = (int)ei[2 * i]; d = (int)ei[2 * (N_EDGES + i)]; }
    else   { s = (int)ei[i];     d = (int)ei[N_EDGES + i]; }
    src[i] = s;
    dst[i] = d;
    atomicAdd(&counts[d], 1);
}

__global__ __launch_bounds__(256) void scan_kernel(const int* __restrict__ counts,
                                                   int* __restrict__ row_start)
{
    __shared__ int lds[256];
    const int t = threadIdx.x;
    int vals[40];
    int tot = 0;
    const int base = t * 40;
#pragma unroll
    for (int j = 0; j < 40; ++j) {
        const int idx = base + j;
        const int c = (idx < N_NODES) ? counts[idx] : 0;
        vals[j] = tot;
        tot += c;
    }
    lds[t] = tot;
    __syncthreads();
    for (int off = 1; off < 256; off <<= 1) {
        const int tmp = (t >= off) ? lds[t - off] : 0;
        __syncthreads();
        lds[t] += tmp;
        __syncthreads();
    }
    const int ebase = lds[t] - tot;
#pragma unroll
    for (int j = 0; j < 40; ++j) {
        const int idx = base + j;
        if (idx < N_NODES) row_start[idx] = ebase + vals[j];
    }
    if (t == 0) row_start[N_NODES] = N_EDGES;
}

__global__ __launch_bounds__(256) void fill_kernel(const int* __restrict__ src,
                                                   const int* __restrict__ dst,
                                                   const int* __restrict__ row_start,
                                                   int* __restrict__ fillc,
                                                   int* __restrict__ csr_eid,
                                                   int* __restrict__ csr_src)
{
    const int i = blockIdx.x * 256 + threadIdx.x;
    if (i >= N_EDGES) return;
    const int d = dst[i];
    const int pos = atomicAdd(&fillc[d], 1);
    const int slot = row_start[d] + pos;
    csr_eid[slot] = i;
    csr_src[slot] = src[i];
}

// ---------------------------------------------------------------------------
// W[k][n] f32 -> wT[n][k] bf16 (tiny; coalesced read, scattered 2B write)
__global__ __launch_bounds__(256) void wconv_kernel(const float* __restrict__ W,
                                                    unsigned short* __restrict__ wT,
                                                    int K, int N)
{
    const int i = blockIdx.x * 256 + threadIdx.x;
    if (i >= K * N) return;
    const int k = i / N, n = i - k * N;
    wT[(size_t)n * K + k] = f2b(W[i]);
}

// ---------------------------------------------------------------------------
// MFMA GEMM: out[M][N] = A[M][K](f32->bf16) @ W (wT = W^T bf16 [N][K]).
// Block: 256 thr = 4 waves, 64-row x 256-col tile; wave owns 64 cols.
// K multiple of 64. gridDim.x = ceil(M/64), gridDim.y = N/256.
// MODE 0: f32 out. MODE 1: bf16 out via LDS-transpose (needs N==256).
// MODE 2: f32 out, ff2 epilogue: out = epi_x + relu(epi_a + acc).
// RELU_A: relu applied to A during staging.
template <int MODE, bool RELU_A>
__global__ __launch_bounds__(256) void mfma_gemm(const float* __restrict__ A,
                                                 const unsigned short* __restrict__ wT,
                                                 void* __restrict__ outv,
                                                 int M, int K, int N,
                                                 const float* __restrict__ epi_a,
                                                 const float* __restrict__ epi_x)
{
    __shared__ __align__(16) char smem[46080];
    unsigned short* a_lds = (unsigned short*)smem;            // [64][72] bf16
    unsigned short* b_lds = (unsigned short*)(smem + 9216);   // [256][72] bf16

    const int tid  = threadIdx.x;
    const int wave = tid >> 6;
    const int lane = tid & 63;
    const int l15  = lane & 15;
    const int l4   = lane >> 4;          // 0..3
    const int m0   = blockIdx.x * 64;
    const int nc0  = blockIdx.y * 256;
    const int wc0  = wave * 64;

    f32x4 acc[4][4];
#pragma unroll
    for (int i = 0; i < 4; ++i)
#pragma unroll
        for (int j = 0; j < 4; ++j) acc[i][j] = f32x4{0.f, 0.f, 0.f, 0.f};

    const int arow = tid >> 2;                     // 0..63
    const int akc  = tid & 3;                      // 16-float chunk
    const int asrc = min(m0 + arow, M - 1);        // clamp (masked at store)

    const int nk = K >> 6;
    for (int kt = 0; kt < nk; ++kt) {
        __syncthreads();
        {   // stage A: 64 rows x 64 k, f32 -> bf16
            const float* src = A + (size_t)asrc * K + kt * 64 + akc * 16;
            unsigned short* dst = a_lds + arow * 72 + akc * 16;
#pragma unroll
            for (int v = 0; v < 4; ++v) {
                float4 f = *(const float4*)(src + v * 4);
                if (RELU_A) {
                    f.x = fmaxf(f.x, 0.f); f.y = fmaxf(f.y, 0.f);
                    f.z = fmaxf(f.z, 0.f); f.w = fmaxf(f.w, 0.f);
                }
                ushort4 u;
                u.x = f2b(f.x); u.y = f2b(f.y); u.z = f2b(f.z); u.w = f2b(f.w);
                *(ushort4*)(dst + v * 4) = u;
            }
        }
        {   // stage B: col = tid, 64 bf16 contiguous from wT (8 x 16B = 128B)
            const unsigned short* src = wT + (size_t)(nc0 + tid) * K + kt * 64;
            unsigned short* dst = b_lds + tid * 72;
#pragma unroll
            for (int v = 0; v < 8; ++v)
                *(uint4*)(dst + v * 8) = *(const uint4*)(src + v * 8);
        }
        __syncthreads();
#pragma unroll
        for (int ks = 0; ks < 2; ++ks) {
            bf16x8 af[4], bf[4];
#pragma unroll
            for (int t = 0; t < 4; ++t)
                af[t] = *(const bf16x8*)(a_lds + (t * 16 + l15) * 72 + ks * 32 + l4 * 8);
#pragma unroll
            for (int t = 0; t < 4; ++t)
                bf[t] = *(const bf16x8*)(b_lds + (wc0 + t * 16 + l15) * 72 + ks * 32 + l4 * 8);
#pragma unroll
            for (int i = 0; i < 4; ++i)
#pragma unroll
                for (int j = 0; j < 4; ++j)
                    acc[i][j] = __builtin_amdgcn_mfma_f32_16x16x32_bf16(af[i], bf[j], acc[i][j], 0, 0, 0);
        }
    }

    if (MODE != 1) {
        float* out = (float*)outv;
#pragma unroll
        for (int i = 0; i < 4; ++i) {
            const int rowb = m0 + i * 16 + l4 * 4;
#pragma unroll
            for (int j = 0; j < 4; ++j) {
                const int col = nc0 + wc0 + j * 16 + l15;
#pragma unroll
                for (int r = 0; r < 4; ++r) {
                    const int grow = rowb + r;
                    if (grow < M) {
                        const size_t oi = (size_t)grow * N + col;
                        float v = acc[i][j][r];
                        if (MODE == 2) {
                            v += epi_a[oi];
                            v = fmaxf(v, 0.f) + epi_x[oi];
                        }
                        out[oi] = v;
                    }
                }
            }
        }
    } else {
        // bf16 out: transpose through LDS, then coalesced 128B stores per thread
        __syncthreads();
        unsigned short* et = (unsigned short*)smem;      // [64][264] bf16 (pad 8)
#pragma unroll
        for (int i = 0; i < 4; ++i) {
            const int rb = i * 16 + l4 * 4;
#pragma unroll
            for (int j = 0; j < 4; ++j) {
                const int col = wc0 + j * 16 + l15;
#pragma unroll
                for (int r = 0; r < 4; ++r)
                    et[(rb + r) * 264 + col] = f2b(acc[i][j][r]);
            }
        }
        __syncthreads();
        unsigned short* outp = (unsigned short*)outv +
                               (size_t)(m0 + (tid >> 2)) * 256 + (tid & 3) * 64;
        const unsigned short* ep = et + (tid >> 2) * 264 + (tid & 3) * 64;
#pragma unroll
        for (int v = 0; v < 8; ++v)
            *(uint4*)(outp + v * 8) = *(const uint4*)(ep + v * 8);
    }
}

// ---------------------------------------------------------------------------
// One propagation hop: h_out[n][d] = sum_{e->n} relu(h_prev1[src][d] + e[d])
//                                    - GAMMA * deg[n] * h_prev2[n][d]
__global__ __launch_bounds__(256) void hop_kernel(const float* __restrict__ h_prev1,
                                                  const float* __restrict__ h_prev2,
                                                  const __hip_bfloat16* __restrict__ e,
                                                  const int* __restrict__ row_start,
                                                  const int* __restrict__ csr_eid,
                                                  const int* __restrict__ csr_src,
                                                  float* __restrict__ h_out)
{
    const int n = blockIdx.x;
    const int t = threadIdx.x;
    const int rb = row_start[n];
    const int re = row_start[n + 1];
    float acc = 0.f;
    for (int s = rb; s < re; ++s) {
        const int eid = csr_eid[s];
        const int sr  = csr_src[s];
        const float v = h_prev1[(size_t)sr * DIM + t] +
                        __bfloat162float(e[(size_t)eid * DIM + t]);
        acc += fmaxf(v, 0.f);
    }
    float r = acc;
    if (h_prev2) {
        const float deg = (float)(re - rb);
        r -= GAMMA * deg * h_prev2[(size_t)n * DIM + t];
    }
    h_out[(size_t)n * DIM + t] = r;
}

// ---------------------------------------------------------------------------
// Hop attention: wave w == head w (64 lanes == 64 head dims).
__global__ __launch_bounds__(256) void attn_kernel(const float* __restrict__ h0,
                                                   const float* __restrict__ h1,
                                                   const float* __restrict__ h2,
                                                   const float* __restrict__ h3,
                                                   const float* __restrict__ att_a,
                                                   float* __restrict__ out)
{
    const int n = blockIdx.x;
    const int t = threadIdx.x;
    const size_t i = (size_t)n * DIM + t;
    const float q = h0[i];
    float hk[4];
    hk[0] = q; hk[1] = h1[i]; hk[2] = h2[i]; hk[3] = h3[i];
    const float a = att_a[t];
    float sc[4];
#pragma unroll
    for (int k = 0; k < 4; ++k) {
        float v = tanhf(hk[k] + q) * a;
#pragma unroll
        for (int off = 32; off > 0; off >>= 1)
            v += __shfl_xor(v, off, 64);
        sc[k] = v;
    }
    const float mx = fmaxf(fmaxf(sc[0], sc[1]), fmaxf(sc[2], sc[3]));
    float ex[4], se = 0.f;
#pragma unroll
    for (int k = 0; k < 4; ++k) { ex[k] = __expf(sc[k] - mx); se += ex[k]; }
    const float inv = 1.f / se;
    float o = 0.f;
#pragma unroll
    for (int k = 0; k < 4; ++k) o += ex[k] * inv * hk[k];
    out[i] = o;
}

// ---------------------------------------------------------------------------
extern "C" void kernel_launch(void* const* d_in, const int* in_sizes, int n_in,
                              void* d_out, int out_size, void* d_ws, size_t ws_size,
                              hipStream_t stream)
{
    const float*    x         = (const float*)d_in[0];
    const unsigned* ei        = (const unsigned*)d_in[1];
    const float*    edge_attr = (const float*)d_in[2];
    const float*    W_x       = (const float*)d_in[3];
    const float*    W_e       = (const float*)d_in[4];
    const float*    att_a     = (const float*)d_in[5];
    const float*    W_ff1     = (const float*)d_in[6];
    const float*    W_ff2     = (const float*)d_in[7];

    char* ws = (char*)d_ws;
    size_t off = 0;
    auto alloc = [&](size_t bytes) -> void* {
        void* p = ws + off;
        off = (off + bytes + 255) & ~(size_t)255;
        return p;
    };
    int*   flag      = (int*)alloc(4);
    int*   src32     = (int*)alloc((size_t)N_EDGES * 4);
    int*   dst32     = (int*)alloc((size_t)N_EDGES * 4);
    int*   counts    = (int*)alloc((size_t)2 * N_NODES * 4);
    int*   fillc     = counts + N_NODES;
    int*   row_start = (int*)alloc((size_t)(N_NODES + 1) * 4);
    int*   csr_eid   = (int*)alloc((size_t)N_EDGES * 4);
    int*   csr_src   = (int*)alloc((size_t)N_EDGES * 4);
    float* h0        = (float*)alloc((size_t)N_NODES * DIM * 4);
    float* h1        = (float*)alloc((size_t)N_NODES * DIM * 4);
    float* h2        = (float*)alloc((size_t)N_NODES * DIM * 4);
    float* h3        = (float*)alloc((size_t)N_NODES * DIM * 4);
    __hip_bfloat16* e_bf = (__hip_bfloat16*)alloc((size_t)N_EDGES * DIM * 2);
    float* attn_out  = (float*)alloc((size_t)N_NODES * DIM * 4);
    float* hidden    = (float*)alloc((size_t)N_NODES * FF_HIDDEN * 4);
    unsigned short* wxT   = (unsigned short*)alloc((size_t)DIM * DIM * 2);
    unsigned short* weT   = (unsigned short*)alloc((size_t)DIM * EDGE_DIM * 2);
    unsigned short* wff1T = (unsigned short*)alloc((size_t)FF_HIDDEN * DIM * 2);
    unsigned short* wff2T = (unsigned short*)alloc((size_t)DIM * FF_HIDDEN * 2);
    if (off > ws_size) return;

    const int egrid = (N_EDGES + 255) / 256;

    hipMemsetAsync(counts, 0, (size_t)2 * N_NODES * 4, stream);
    detect_kernel<<<1, 256, 0, stream>>>(ei, flag);
    convert_kernel<<<egrid, 256, 0, stream>>>(ei, flag, src32, dst32, counts);
    scan_kernel<<<1, 256, 0, stream>>>(counts, row_start);
    fill_kernel<<<egrid, 256, 0, stream>>>(src32, dst32, row_start, fillc, csr_eid, csr_src);

    wconv_kernel<<<(DIM * DIM + 255) / 256, 256, 0, stream>>>(W_x, wxT, DIM, DIM);
    wconv_kernel<<<(EDGE_DIM * DIM + 255) / 256, 256, 0, stream>>>(W_e, weT, EDGE_DIM, DIM);
    wconv_kernel<<<(DIM * FF_HIDDEN + 255) / 256, 256, 0, stream>>>(W_ff1, wff1T, DIM, FF_HIDDEN);
    wconv_kernel<<<(FF_HIDDEN * DIM + 255) / 256, 256, 0, stream>>>(W_ff2, wff2T, FF_HIDDEN, DIM);

    // h0 = x @ W_x   (M=10000, K=256, N=256)
    mfma_gemm<0, false><<<dim3(157, 1), 256, 0, stream>>>(x, wxT, h0,
        N_NODES, DIM, DIM, nullptr, nullptr);
    // e = edge_attr @ W_e -> bf16   (M=320000, K=64, N=256)
    mfma_gemm<1, false><<<dim3(N_EDGES / 64, 1), 256, 0, stream>>>(edge_attr, weT, e_bf,
        N_EDGES, EDGE_DIM, DIM, nullptr, nullptr);

    hop_kernel<<<N_NODES, 256, 0, stream>>>(h0, nullptr, e_bf, row_start, csr_eid, csr_src, h1);
    hop_kernel<<<N_NODES, 256, 0, stream>>>(h1, h0,      e_bf, row_start, csr_eid, csr_src, h2);
    hop_kernel<<<N_NODES, 256, 0, stream>>>(h2, h1,      e_bf, row_start, csr_eid, csr_src, h3);

    attn_kernel<<<N_NODES, 256, 0, stream>>>(h0, h1, h2, h3, att_a, attn_out);

    // hidden = attn_out @ W_ff1   (M=10000, K=256, N=512)
    mfma_gemm<0, false><<<dim3(157, 2), 256, 0, stream>>>(attn_out, wff1T, hidden,
        N_NODES, DIM, FF_HIDDEN, nullptr, nullptr);
    // d_out = x + relu(attn_out + relu(hidden) @ W_ff2)   (M=10000, K=512, N=256)
    mfma_gemm<2, true><<<dim3(157, 1), 256, 0, stream>>>(hidden, wff2T, d_out,
        N_NODES, FF_HIDDEN, DIM, attn_out, x);
}

// Round 5
// 429.894 us; speedup vs baseline: 2.1530x; 1.1152x over previous
//
#include <hip/hip_runtime.h>
#include <hip/hip_bf16.h>

#define N_NODES   10000
#define N_EDGES   320000
#define DIM       256
#define EDGE_DIM  64
#define FF_HIDDEN 512
#define GAMMA     0.5f

typedef __attribute__((ext_vector_type(8))) short bf16x8;
typedef __attribute__((ext_vector_type(4))) float f32x4;

static __device__ __forceinline__ unsigned short f2b(float f)
{
    union { __hip_bfloat16 b; unsigned short u; } c;
    c.b = __float2bfloat16(f);
    return c.u;
}

// ---------------------------------------------------------------------------
// Edge-index dtype probe: int64 little-endian with values <2^31 has zero high
// words; int32 random values in [0,10000) make P(1024 zeros) ~ 0.
__global__ __launch_bounds__(256) void detect_kernel(const unsigned* __restrict__ ei,
                                                     int* __restrict__ flag)
{
    __shared__ int bad;
    if (threadIdx.x == 0) bad = 0;
    __syncthreads();
    int b = 0;
    for (int i = threadIdx.x; i < 1024; i += 256)
        if (ei[2 * i + 1] != 0u) b = 1;
    if (b) atomicAdd(&bad, 1);
    __syncthreads();
    if (threadIdx.x == 0) *flag = (bad == 0) ? 1 : 0;
}

__global__ __launch_bounds__(256) void convert_kernel(const unsigned* __restrict__ ei,
                                                      const int* __restrict__ flag,
                                                      int* __restrict__ src, int* __restrict__ dst,
                                                      int* __restrict__ counts)
{
    const int i = blockIdx.x * 256 + threadIdx.x;
    if (i >= N_EDGES) return;
    const int f = *flag;
    int s, d;
    if (f) { s = (int)ei[2 * i]; d = (int)ei[2 * (N_EDGES + i)]; }
    else   { s = (int)ei[i];     d = (int)ei[N_EDGES + i]; }
    src[i] = s;
    dst[i] = d;
    atomicAdd(&counts[d], 1);
}

__global__ __launch_bounds__(256) void scan_kernel(const int* __restrict__ counts,
                                                   int* __restrict__ row_start)
{
    __shared__ int lds[256];
    const int t = threadIdx.x;
    int vals[40];
    int tot = 0;
    const int base = t * 40;
#pragma unroll
    for (int j = 0; j < 40; ++j) {
        const int idx = base + j;
        const int c = (idx < N_NODES) ? counts[idx] : 0;
        vals[j] = tot;
        tot += c;
    }
    lds[t] = tot;
    __syncthreads();
    for (int off = 1; off < 256; off <<= 1) {
        const int tmp = (t >= off) ? lds[t - off] : 0;
        __syncthreads();
        lds[t] += tmp;
        __syncthreads();
    }
    const int ebase = lds[t] - tot;
#pragma unroll
    for (int j = 0; j < 40; ++j) {
        const int idx = base + j;
        if (idx < N_NODES) row_start[idx] = ebase + vals[j];
    }
    if (t == 0) row_start[N_NODES] = N_EDGES;
}

// Also records perm[edge] = CSR slot so e can be written pre-permuted.
__global__ __launch_bounds__(256) void fill_kernel(const int* __restrict__ src,
                                                   const int* __restrict__ dst,
                                                   const int* __restrict__ row_start,
                                                   int* __restrict__ fillc,
                                                   int* __restrict__ perm,
                                                   int* __restrict__ csr_src)
{
    const int i = blockIdx.x * 256 + threadIdx.x;
    if (i >= N_EDGES) return;
    const int d = dst[i];
    const int pos = atomicAdd(&fillc[d], 1);
    const int slot = row_start[d] + pos;
    perm[i] = slot;
    csr_src[slot] = src[i];
}

// ---------------------------------------------------------------------------
// W[k][n] f32 -> wT[n][k] bf16 (tiny; coalesced read, scattered 2B write)
__global__ __launch_bounds__(256) void wconv_kernel(const float* __restrict__ W,
                                                    unsigned short* __restrict__ wT,
                                                    int K, int N)
{
    const int i = blockIdx.x * 256 + threadIdx.x;
    if (i >= K * N) return;
    const int k = i / N, n = i - k * N;
    wT[(size_t)n * K + k] = f2b(W[i]);
}

// ---------------------------------------------------------------------------
// MFMA GEMM: out[M][N] = A[M][K](f32->bf16) @ W (wT = W^T bf16 [N][K]).
// Block: 256 thr = 4 waves, 64-row x 256-col tile; wave owns 64 cols.
// K multiple of 64. gridDim.x = ceil(M/64), gridDim.y = N/256.
// MODE 0: f32 out. MODE 1: bf16 out via LDS-transpose (needs N==256); rows
//   scatter to perm[m] when perm != nullptr.
// MODE 2: f32 out, ff2 epilogue: out = epi_x + relu(epi_a + acc).
// RELU_A: relu applied to A during staging.
template <int MODE, bool RELU_A>
__global__ __launch_bounds__(256) void mfma_gemm(const float* __restrict__ A,
                                                 const unsigned short* __restrict__ wT,
                                                 void* __restrict__ outv,
                                                 int M, int K, int N,
                                                 const float* __restrict__ epi_a,
                                                 const float* __restrict__ epi_x,
                                                 const int* __restrict__ perm)
{
    __shared__ __align__(16) char smem[46080];
    unsigned short* a_lds = (unsigned short*)smem;            // [64][72] bf16
    unsigned short* b_lds = (unsigned short*)(smem + 9216);   // [256][72] bf16

    const int tid  = threadIdx.x;
    const int wave = tid >> 6;
    const int lane = tid & 63;
    const int l15  = lane & 15;
    const int l4   = lane >> 4;          // 0..3
    const int m0   = blockIdx.x * 64;
    const int nc0  = blockIdx.y * 256;
    const int wc0  = wave * 64;

    f32x4 acc[4][4];
#pragma unroll
    for (int i = 0; i < 4; ++i)
#pragma unroll
        for (int j = 0; j < 4; ++j) acc[i][j] = f32x4{0.f, 0.f, 0.f, 0.f};

    const int arow = tid >> 2;                     // 0..63
    const int akc  = tid & 3;                      // 16-float chunk
    const int asrc = min(m0 + arow, M - 1);        // clamp (masked at store)

    const int nk = K >> 6;
    for (int kt = 0; kt < nk; ++kt) {
        __syncthreads();
        {   // stage A: 64 rows x 64 k, f32 -> bf16
            const float* src = A + (size_t)asrc * K + kt * 64 + akc * 16;
            unsigned short* dst = a_lds + arow * 72 + akc * 16;
#pragma unroll
            for (int v = 0; v < 4; ++v) {
                float4 f = *(const float4*)(src + v * 4);
                if (RELU_A) {
                    f.x = fmaxf(f.x, 0.f); f.y = fmaxf(f.y, 0.f);
                    f.z = fmaxf(f.z, 0.f); f.w = fmaxf(f.w, 0.f);
                }
                ushort4 u;
                u.x = f2b(f.x); u.y = f2b(f.y); u.z = f2b(f.z); u.w = f2b(f.w);
                *(ushort4*)(dst + v * 4) = u;
            }
        }
        {   // stage B: col = tid, 64 bf16 contiguous from wT (8 x 16B = 128B)
            const unsigned short* src = wT + (size_t)(nc0 + tid) * K + kt * 64;
            unsigned short* dst = b_lds + tid * 72;
#pragma unroll
            for (int v = 0; v < 8; ++v)
                *(uint4*)(dst + v * 8) = *(const uint4*)(src + v * 8);
        }
        __syncthreads();
#pragma unroll
        for (int ks = 0; ks < 2; ++ks) {
            bf16x8 af[4], bf[4];
#pragma unroll
            for (int t = 0; t < 4; ++t)
                af[t] = *(const bf16x8*)(a_lds + (t * 16 + l15) * 72 + ks * 32 + l4 * 8);
#pragma unroll
            for (int t = 0; t < 4; ++t)
                bf[t] = *(const bf16x8*)(b_lds + (wc0 + t * 16 + l15) * 72 + ks * 32 + l4 * 8);
#pragma unroll
            for (int i = 0; i < 4; ++i)
#pragma unroll
                for (int j = 0; j < 4; ++j)
                    acc[i][j] = __builtin_amdgcn_mfma_f32_16x16x32_bf16(af[i], bf[j], acc[i][j], 0, 0, 0);
        }
    }

    if (MODE != 1) {
        float* out = (float*)outv;
#pragma unroll
        for (int i = 0; i < 4; ++i) {
            const int rowb = m0 + i * 16 + l4 * 4;
#pragma unroll
            for (int j = 0; j < 4; ++j) {
                const int col = nc0 + wc0 + j * 16 + l15;
#pragma unroll
                for (int r = 0; r < 4; ++r) {
                    const int grow = rowb + r;
                    if (grow < M) {
                        const size_t oi = (size_t)grow * N + col;
                        float v = acc[i][j][r];
                        if (MODE == 2) {
                            v += epi_a[oi];
                            v = fmaxf(v, 0.f) + epi_x[oi];
                        }
                        out[oi] = v;
                    }
                }
            }
        }
    } else {
        // bf16 out: transpose through LDS, then coalesced 128B stores per
        // thread; destination row optionally permuted (CSR scatter).
        __syncthreads();
        unsigned short* et = (unsigned short*)smem;      // [64][264] bf16 (pad 8)
#pragma unroll
        for (int i = 0; i < 4; ++i) {
            const int rb = i * 16 + l4 * 4;
#pragma unroll
            for (int j = 0; j < 4; ++j) {
                const int col = wc0 + j * 16 + l15;
#pragma unroll
                for (int r = 0; r < 4; ++r)
                    et[(rb + r) * 264 + col] = f2b(acc[i][j][r]);
            }
        }
        __syncthreads();
        const int lrow = tid >> 2;
        const int orow = perm ? perm[m0 + lrow] : (m0 + lrow);
        unsigned short* outp = (unsigned short*)outv +
                               (size_t)orow * 256 + (tid & 3) * 64;
        const unsigned short* ep = et + lrow * 264 + (tid & 3) * 64;
#pragma unroll
        for (int v = 0; v < 8; ++v)
            *(uint4*)(outp + v * 8) = *(const uint4*)(ep + v * 8);
    }
}

// ---------------------------------------------------------------------------
// One propagation hop. e is pre-permuted to CSR order: row s of e belongs to
// CSR slot s, so e reads are a pure sequential stream (no indirection).
// h_out[n][d] = sum_{s in [rb,re)} relu(h_prev1[csr_src[s]][d] + e[s][d])
//               - GAMMA * deg[n] * h_prev2[n][d]
__global__ __launch_bounds__(256) void hop_kernel(const float* __restrict__ h_prev1,
                                                  const float* __restrict__ h_prev2,
                                                  const __hip_bfloat16* __restrict__ e,
                                                  const int* __restrict__ row_start,
                                                  const int* __restrict__ csr_src,
                                                  float* __restrict__ h_out)
{
    const int n = blockIdx.x;
    const int t = threadIdx.x;
    const int rb = row_start[n];
    const int re = row_start[n + 1];
    float acc = 0.f;
    int s = rb;
    for (; s + 4 <= re; s += 4) {
        const int i0 = csr_src[s];
        const int i1 = csr_src[s + 1];
        const int i2 = csr_src[s + 2];
        const int i3 = csr_src[s + 3];
        const float e0 = __bfloat162float(e[(size_t)(s + 0) * DIM + t]);
        const float e1 = __bfloat162float(e[(size_t)(s + 1) * DIM + t]);
        const float e2 = __bfloat162float(e[(size_t)(s + 2) * DIM + t]);
        const float e3 = __bfloat162float(e[(size_t)(s + 3) * DIM + t]);
        const float h0v = h_prev1[(size_t)i0 * DIM + t];
        const float h1v = h_prev1[(size_t)i1 * DIM + t];
        const float h2v = h_prev1[(size_t)i2 * DIM + t];
        const float h3v = h_prev1[(size_t)i3 * DIM + t];
        acc += fmaxf(h0v + e0, 0.f) + fmaxf(h1v + e1, 0.f) +
               fmaxf(h2v + e2, 0.f) + fmaxf(h3v + e3, 0.f);
    }
    for (; s < re; ++s) {
        const int sr = csr_src[s];
        const float v = h_prev1[(size_t)sr * DIM + t] +
                        __bfloat162float(e[(size_t)s * DIM + t]);
        acc += fmaxf(v, 0.f);
    }
    float r = acc;
    if (h_prev2) {
        const float deg = (float)(re - rb);
        r -= GAMMA * deg * h_prev2[(size_t)n * DIM + t];
    }
    h_out[(size_t)n * DIM + t] = r;
}

// ---------------------------------------------------------------------------
// Hop attention: wave w == head w (64 lanes == 64 head dims).
__global__ __launch_bounds__(256) void attn_kernel(const float* __restrict__ h0,
                                                   const float* __restrict__ h1,
                                                   const float* __restrict__ h2,
                                                   const float* __restrict__ h3,
                                                   const float* __restrict__ att_a,
                                                   float* __restrict__ out)
{
    const int n = blockIdx.x;
    const int t = threadIdx.x;
    const size_t i = (size_t)n * DIM + t;
    const float q = h0[i];
    float hk[4];
    hk[0] = q; hk[1] = h1[i]; hk[2] = h2[i]; hk[3] = h3[i];
    const float a = att_a[t];
    float sc[4];
#pragma unroll
    for (int k = 0; k < 4; ++k) {
        float v = tanhf(hk[k] + q) * a;
#pragma unroll
        for (int off = 32; off > 0; off >>= 1)
            v += __shfl_xor(v, off, 64);
        sc[k] = v;
    }
    const float mx = fmaxf(fmaxf(sc[0], sc[1]), fmaxf(sc[2], sc[3]));
    float ex[4], se = 0.f;
#pragma unroll
    for (int k = 0; k < 4; ++k) { ex[k] = __expf(sc[k] - mx); se += ex[k]; }
    const float inv = 1.f / se;
    float o = 0.f;
#pragma unroll
    for (int k = 0; k < 4; ++k) o += ex[k] * inv * hk[k];
    out[i] = o;
}

// ---------------------------------------------------------------------------
extern "C" void kernel_launch(void* const* d_in, const int* in_sizes, int n_in,
                              void* d_out, int out_size, void* d_ws, size_t ws_size,
                              hipStream_t stream)
{
    const float*    x         = (const float*)d_in[0];
    const unsigned* ei        = (const unsigned*)d_in[1];
    const float*    edge_attr = (const float*)d_in[2];
    const float*    W_x       = (const float*)d_in[3];
    const float*    W_e       = (const float*)d_in[4];
    const float*    att_a     = (const float*)d_in[5];
    const float*    W_ff1     = (const float*)d_in[6];
    const float*    W_ff2     = (const float*)d_in[7];

    char* ws = (char*)d_ws;
    size_t off = 0;
    auto alloc = [&](size_t bytes) -> void* {
        void* p = ws + off;
        off = (off + bytes + 255) & ~(size_t)255;
        return p;
    };
    int*   flag      = (int*)alloc(4);
    int*   src32     = (int*)alloc((size_t)N_EDGES * 4);
    int*   dst32     = (int*)alloc((size_t)N_EDGES * 4);
    int*   counts    = (int*)alloc((size_t)2 * N_NODES * 4);
    int*   fillc     = counts + N_NODES;
    int*   row_start = (int*)alloc((size_t)(N_NODES + 1) * 4);
    int*   perm      = (int*)alloc((size_t)N_EDGES * 4);
    int*   csr_src   = (int*)alloc((size_t)N_EDGES * 4);
    float* h0        = (float*)alloc((size_t)N_NODES * DIM * 4);
    float* h1        = (float*)alloc((size_t)N_NODES * DIM * 4);
    float* h2        = (float*)alloc((size_t)N_NODES * DIM * 4);
    float* h3        = (float*)alloc((size_t)N_NODES * DIM * 4);
    __hip_bfloat16* e_bf = (__hip_bfloat16*)alloc((size_t)N_EDGES * DIM * 2);
    float* attn_out  = (float*)alloc((size_t)N_NODES * DIM * 4);
    float* hidden    = (float*)alloc((size_t)N_NODES * FF_HIDDEN * 4);
    unsigned short* wxT   = (unsigned short*)alloc((size_t)DIM * DIM * 2);
    unsigned short* weT   = (unsigned short*)alloc((size_t)DIM * EDGE_DIM * 2);
    unsigned short* wff1T = (unsigned short*)alloc((size_t)FF_HIDDEN * DIM * 2);
    unsigned short* wff2T = (unsigned short*)alloc((size_t)DIM * FF_HIDDEN * 2);
    if (off > ws_size) return;

    const int egrid = (N_EDGES + 255) / 256;

    hipMemsetAsync(counts, 0, (size_t)2 * N_NODES * 4, stream);
    detect_kernel<<<1, 256, 0, stream>>>(ei, flag);
    convert_kernel<<<egrid, 256, 0, stream>>>(ei, flag, src32, dst32, counts);
    scan_kernel<<<1, 256, 0, stream>>>(counts, row_start);
    fill_kernel<<<egrid, 256, 0, stream>>>(src32, dst32, row_start, fillc, perm, csr_src);

    wconv_kernel<<<(DIM * DIM + 255) / 256, 256, 0, stream>>>(W_x, wxT, DIM, DIM);
    wconv_kernel<<<(EDGE_DIM * DIM + 255) / 256, 256, 0, stream>>>(W_e, weT, EDGE_DIM, DIM);
    wconv_kernel<<<(DIM * FF_HIDDEN + 255) / 256, 256, 0, stream>>>(W_ff1, wff1T, DIM, FF_HIDDEN);
    wconv_kernel<<<(FF_HIDDEN * DIM + 255) / 256, 256, 0, stream>>>(W_ff2, wff2T, FF_HIDDEN, DIM);

    // h0 = x @ W_x   (M=10000, K=256, N=256)
    mfma_gemm<0, false><<<dim3(157, 1), 256, 0, stream>>>(x, wxT, h0,
        N_NODES, DIM, DIM, nullptr, nullptr, nullptr);
    // e = edge_attr @ W_e -> bf16, rows scattered to CSR slots
    mfma_gemm<1, false><<<dim3(N_EDGES / 64, 1), 256, 0, stream>>>(edge_attr, weT, e_bf,
        N_EDGES, EDGE_DIM, DIM, nullptr, nullptr, perm);

    hop_kernel<<<N_NODES, 256, 0, stream>>>(h0, nullptr, e_bf, row_start, csr_src, h1);
    hop_kernel<<<N_NODES, 256, 0, stream>>>(h1, h0,      e_bf, row_start, csr_src, h2);
    hop_kernel<<<N_NODES, 256, 0, stream>>>(h2, h1,      e_bf, row_start, csr_src, h3);

    attn_kernel<<<N_NODES, 256, 0, stream>>>(h0, h1, h2, h3, att_a, attn_out);

    // hidden = attn_out @ W_ff1   (M=10000, K=256, N=512)
    mfma_gemm<0, false><<<dim3(157, 2), 256, 0, stream>>>(attn_out, wff1T, hidden,
        N_NODES, DIM, FF_HIDDEN, nullptr, nullptr, nullptr);
    // d_out = x + relu(attn_out + relu(hidden) @ W_ff2)   (M=10000, K=512, N=256)
    mfma_gemm<2, true><<<dim3(157, 1), 256, 0, stream>>>(hidden, wff2T, d_out,
        N_NODES, FF_HIDDEN, DIM, attn_out, x, nullptr);
}